// Round 1
// baseline (1044.542 us; speedup 1.0000x reference)
//
#include <hip/hip_runtime.h>

#define NUM_COND 16
#define FDIM 128
#define EPS 1e-5f
// per-block ws region, in floats: s1[2048] (swizzled) + s2[2048] (swizzled) + cnt[16]
#define PB 4112

// LDS swizzle: feature f stored at p = (f&3)*32 + (f>>2)
// inverse: f = ((p&31)<<2) | (p>>5)

__global__ __launch_bounds__(512) void cbn_stats_kernel(
    const float* __restrict__ x, const int* __restrict__ labels,
    float* __restrict__ ws, int N, int nblocks)
{
    __shared__ float s1[2048];
    __shared__ float s2[2048];
    __shared__ float cnt[NUM_COND];
    const int t = threadIdx.x;
    for (int i = t; i < 2048; i += 512) { s1[i] = 0.f; s2[i] = 0.f; }
    if (t < NUM_COND) cnt[t] = 0.f;
    __syncthreads();

    const int f4 = t & 31;        // which float4 of the row (0..31)
    const int rg = t >> 5;        // row group within block (0..15)
    const int rpi = 512 / 32;     // 16 rows per block iteration
    const float4* x4 = (const float4*)x;

    for (int r = blockIdx.x * rpi + rg; r < N; r += nblocks * rpi) {
        const int lab = labels[r];
        const float4 v = x4[(size_t)r * 32 + f4];
        const int base = lab * FDIM + f4;   // p = j*32 + f4 (swizzled, conflict-free)
        atomicAdd(&s1[base     ], v.x);
        atomicAdd(&s2[base     ], v.x * v.x);
        atomicAdd(&s1[base + 32], v.y);
        atomicAdd(&s2[base + 32], v.y * v.y);
        atomicAdd(&s1[base + 64], v.z);
        atomicAdd(&s2[base + 64], v.z * v.z);
        atomicAdd(&s1[base + 96], v.w);
        atomicAdd(&s2[base + 96], v.w * v.w);
        if (f4 == 0) atomicAdd(&cnt[lab], 1.0f);
    }
    __syncthreads();

    float* out = ws + (size_t)blockIdx.x * PB;
    for (int i = t; i < 2048; i += 512) {
        out[i]        = s1[i];
        out[2048 + i] = s2[i];
    }
    if (t < NUM_COND) out[4096 + t] = cnt[t];
}

__global__ __launch_bounds__(256) void cbn_finalize_kernel(
    const float* __restrict__ ws, const float* __restrict__ gamma,
    const float* __restrict__ beta, float* __restrict__ scale_shift,
    int nblocks)
{
    __shared__ float csum[NUM_COND];
    const int t = threadIdx.x;
    const int e = blockIdx.x * 256 + t;   // 0..2047 (swizzled entry index)
    if (t < NUM_COND) {
        float c = 0.f;
        for (int b = 0; b < nblocks; ++b) c += ws[(size_t)b * PB + 4096 + t];
        csum[t] = fmaxf(c, 1.0f);
    }
    __syncthreads();
    float a1 = 0.f, a2 = 0.f;
    for (int b = 0; b < nblocks; ++b) {
        const float* p = ws + (size_t)b * PB;
        a1 += p[e];            // coalesced across threads
        a2 += p[2048 + e];
    }
    const int c = e >> 7;
    const int p = e & 127;
    const int f = ((p & 31) << 2) | (p >> 5);   // unswizzle
    const float cn = csum[c];
    const float mean = a1 / cn;
    const float var  = a2 / cn - mean * mean;
    const float sc = gamma[c * FDIM + f] * rsqrtf(var + EPS);
    const float sh = beta[c * FDIM + f] - mean * sc;
    scale_shift[c * FDIM + f]        = sc;
    scale_shift[2048 + c * FDIM + f] = sh;
}

__global__ __launch_bounds__(256) void cbn_apply_kernel(
    const float* __restrict__ x, const int* __restrict__ labels,
    const float* __restrict__ scale_shift, float* __restrict__ y, int N)
{
    __shared__ float4 ssc[NUM_COND * 32];
    __shared__ float4 ssh[NUM_COND * 32];
    const int t = threadIdx.x;
    const float4* ss4 = (const float4*)scale_shift;
    for (int i = t; i < NUM_COND * 32; i += 256) {
        ssc[i] = ss4[i];
        ssh[i] = ss4[512 + i];
    }
    __syncthreads();

    const int f4 = t & 31;
    const int rg = t >> 5;        // 0..7
    const int rpi = 256 / 32;     // 8 rows per block iteration
    const float4* x4 = (const float4*)x;
    float4* y4 = (float4*)y;

    for (int r = blockIdx.x * rpi + rg; r < N; r += gridDim.x * rpi) {
        const int lab = labels[r];
        const float4 v  = x4[(size_t)r * 32 + f4];
        const float4 sc = ssc[lab * 32 + f4];
        const float4 sh = ssh[lab * 32 + f4];
        float4 o;
        o.x = v.x * sc.x + sh.x;
        o.y = v.y * sc.y + sh.y;
        o.z = v.z * sc.z + sh.z;
        o.w = v.w * sc.w + sh.w;
        y4[(size_t)r * 32 + f4] = o;
    }
}

extern "C" void kernel_launch(void* const* d_in, const int* in_sizes, int n_in,
                              void* d_out, int out_size, void* d_ws, size_t ws_size,
                              hipStream_t stream)
{
    const float* x      = (const float*)d_in[0];
    const int*   labels = (const int*)d_in[1];
    const float* gamma  = (const float*)d_in[2];
    const float* beta   = (const float*)d_in[3];
    float* y  = (float*)d_out;
    float* ws = (float*)d_ws;
    const int N = in_sizes[1];   // labels element count

    // adapt stats grid to available workspace
    long floats = (long)(ws_size / sizeof(float));
    long avail  = floats - 4096;             // reserve scale/shift footer
    int nb = 512;
    if ((long)nb * PB > avail) nb = (int)(avail / PB);
    if (nb < 1) nb = 1;
    float* scale_shift = ws + (size_t)nb * PB;

    cbn_stats_kernel<<<nb, 512, 0, stream>>>(x, labels, ws, N, nb);
    cbn_finalize_kernel<<<8, 256, 0, stream>>>(ws, gamma, beta, scale_shift, nb);
    cbn_apply_kernel<<<2048, 256, 0, stream>>>(x, labels, scale_shift, y, N);
}

// Round 2
// 250.041 us; speedup vs baseline: 4.1775x; 4.1775x over previous
//
#include <hip/hip_runtime.h>

#define NUM_COND 16
#define FDIM 128
#define EPS 1e-5f
#define PB 4112      // floats per partial: s1[2048] + s2[2048] + cnt[16]
#define NCHUNK 16
#define MAXNB 512

// Accumulate one float2 (2 features per lane) into per-label register accumulators.
// Compile-time label index c -> stays in registers (no scratch).
#define ACC(c, v)                                                     \
    a1x[c] += (v).x; a1y[c] += (v).y;                                 \
    a2x[c] = fmaf((v).x, (v).x, a2x[c]);                              \
    a2y[c] = fmaf((v).y, (v).y, a2y[c]);                              \
    cw[c] += 1;

// Label is wave-uniform (one wave == one row) -> scalar switch, no divergence.
#define PROCESS(v, lab)                                               \
    switch (__builtin_amdgcn_readfirstlane(lab)) {                    \
      case 0:  ACC(0,  v) break;  case 1:  ACC(1,  v) break;          \
      case 2:  ACC(2,  v) break;  case 3:  ACC(3,  v) break;          \
      case 4:  ACC(4,  v) break;  case 5:  ACC(5,  v) break;          \
      case 6:  ACC(6,  v) break;  case 7:  ACC(7,  v) break;          \
      case 8:  ACC(8,  v) break;  case 9:  ACC(9,  v) break;          \
      case 10: ACC(10, v) break;  case 11: ACC(11, v) break;          \
      case 12: ACC(12, v) break;  case 13: ACC(13, v) break;          \
      case 14: ACC(14, v) break;  case 15: ACC(15, v) break;          \
      default: break;                                                 \
    }

__global__ __launch_bounds__(256) void cbn_stats_kernel(
    const float* __restrict__ x, const int* __restrict__ labels,
    float* __restrict__ ws, int N, int nb, int chunk)
{
    const int t    = threadIdx.x;
    const int w    = t >> 6;     // wave 0..3
    const int lane = t & 63;     // lane covers features 2*lane, 2*lane+1

    float a1x[16], a1y[16], a2x[16], a2y[16];
    int cw[16];
#pragma unroll
    for (int c = 0; c < 16; ++c) { a1x[c]=0.f; a1y[c]=0.f; a2x[c]=0.f; a2y[c]=0.f; cw[c]=0; }

    const int rbeg = blockIdx.x * chunk;
    const int rend = min(N, rbeg + chunk);
    const float2* x2 = (const float2*)x;

    // two independent row streams per wave, 2-deep pipeline -> 4 loads in flight
    int rA = rbeg + w;
    int rB = rbeg + w + 4;
    float2 vA, vB; int labA = 0, labB = 0;
    bool okA = rA < rend, okB = rB < rend;
    if (okA) { vA = x2[(size_t)rA * 64 + lane]; labA = labels[rA]; }
    if (okB) { vB = x2[(size_t)rB * 64 + lane]; labB = labels[rB]; }

    while (okA) {
        const int rA2 = rA + 8, rB2 = rB + 8;
        float2 vA2, vB2; int labA2 = 0, labB2 = 0;
        const bool okA2 = rA2 < rend, okB2 = rB2 < rend;
        if (okA2) { vA2 = x2[(size_t)rA2 * 64 + lane]; labA2 = labels[rA2]; }
        if (okB2) { vB2 = x2[(size_t)rB2 * 64 + lane]; labB2 = labels[rB2]; }

        PROCESS(vA, labA)
        if (okB) { PROCESS(vB, labB) }

        rA = rA2; rB = rB2; vA = vA2; vB = vB2; labA = labA2; labB = labB2;
        okA = okA2; okB = okB2;
    }

    // block merge: phased non-atomic LDS accumulation (4 waves -> 4 phases)
    __shared__ float s1[2048];
    __shared__ float s2[2048];
    __shared__ float scnt[NUM_COND];
    for (int i = t; i < 2048; i += 256) { s1[i] = 0.f; s2[i] = 0.f; }
    if (t < NUM_COND) scnt[t] = 0.f;
    __syncthreads();

    for (int ph = 0; ph < 4; ++ph) {
        if (w == ph) {
#pragma unroll
            for (int c = 0; c < 16; ++c) {
                const int idx = c * FDIM + 2 * lane;
                s1[idx]     += a1x[c];
                s1[idx + 1] += a1y[c];
                s2[idx]     += a2x[c];
                s2[idx + 1] += a2y[c];
            }
            if (lane == 0) {
#pragma unroll
                for (int c = 0; c < 16; ++c) scnt[c] += (float)cw[c];
            }
        }
        __syncthreads();
    }

    float* out = ws + (size_t)blockIdx.x * PB;
    for (int i = t; i < 2048; i += 256) { out[i] = s1[i]; out[2048 + i] = s2[i]; }
    if (t < NUM_COND) out[4096 + t] = scnt[t];
}

// stage 1 reduce: sum partials in NCHUNK chunks; grid = (ceil(PB/256), NCHUNK)
__global__ __launch_bounds__(256) void cbn_reduce_kernel(
    const float* __restrict__ ws, float* __restrict__ ws2, int nb, int per)
{
    const int e = blockIdx.x * 256 + threadIdx.x;
    if (e >= PB) return;
    const int b0 = blockIdx.y * per;
    const int b1 = min(nb, b0 + per);
    float a = 0.f;
#pragma unroll 4
    for (int b = b0; b < b1; ++b) a += ws[(size_t)b * PB + e];
    ws2[(size_t)blockIdx.y * PB + e] = a;
}

// stage 2: reduce NCHUNK chunk-partials, compute scale/shift. grid = 8 x 256
__global__ __launch_bounds__(256) void cbn_finalize_kernel(
    const float* __restrict__ ws2, const float* __restrict__ gamma,
    const float* __restrict__ beta, float* __restrict__ scale_shift)
{
    const int e = blockIdx.x * 256 + threadIdx.x;   // 0..2047 = c*128+f
    float a1 = 0.f, a2 = 0.f, cn = 0.f;
#pragma unroll
    for (int k = 0; k < NCHUNK; ++k) {
        const float* p = ws2 + (size_t)k * PB;
        a1 += p[e];
        a2 += p[2048 + e];
        cn += p[4096 + (e >> 7)];
    }
    cn = fmaxf(cn, 1.0f);
    const float mean = a1 / cn;
    const float var  = a2 / cn - mean * mean;
    const float sc = gamma[e] * rsqrtf(var + EPS);
    const float sh = beta[e] - mean * sc;
    scale_shift[e]        = sc;
    scale_shift[2048 + e] = sh;
}

__global__ __launch_bounds__(256) void cbn_apply_kernel(
    const float* __restrict__ x, const int* __restrict__ labels,
    const float* __restrict__ scale_shift, float* __restrict__ y, int N)
{
    __shared__ float4 ssc[NUM_COND * 32];
    __shared__ float4 ssh[NUM_COND * 32];
    const int t = threadIdx.x;
    const float4* ss4 = (const float4*)scale_shift;
    for (int i = t; i < NUM_COND * 32; i += 256) {
        ssc[i] = ss4[i];
        ssh[i] = ss4[512 + i];
    }
    __syncthreads();

    const int f4 = t & 31;
    const int rg = t >> 5;                 // 0..7
    const float4* x4 = (const float4*)x;
    float4* y4 = (float4*)y;

    // 4 rows per thread per iteration -> 8 load-pairs in flight per wave
    for (int base = blockIdx.x * 32 + rg; base < N; base += gridDim.x * 32) {
        const int r0 = base;
        int r1 = base + 8, r2 = base + 16, r3 = base + 24;
        const bool k1 = r1 < N, k2 = r2 < N, k3 = r3 < N;
        if (!k1) r1 = r0;  if (!k2) r2 = r0;  if (!k3) r3 = r0;  // clamp: loads stay in-bounds

        const int l0 = labels[r0], l1 = labels[r1], l2 = labels[r2], l3 = labels[r3];
        const float4 v0 = x4[(size_t)r0 * 32 + f4];
        const float4 v1 = x4[(size_t)r1 * 32 + f4];
        const float4 v2 = x4[(size_t)r2 * 32 + f4];
        const float4 v3 = x4[(size_t)r3 * 32 + f4];

        const float4 c0 = ssc[l0 * 32 + f4], h0 = ssh[l0 * 32 + f4];
        const float4 c1 = ssc[l1 * 32 + f4], h1 = ssh[l1 * 32 + f4];
        const float4 c2 = ssc[l2 * 32 + f4], h2 = ssh[l2 * 32 + f4];
        const float4 c3 = ssc[l3 * 32 + f4], h3 = ssh[l3 * 32 + f4];

        float4 o0, o1, o2, o3;
        o0.x = fmaf(v0.x, c0.x, h0.x); o0.y = fmaf(v0.y, c0.y, h0.y);
        o0.z = fmaf(v0.z, c0.z, h0.z); o0.w = fmaf(v0.w, c0.w, h0.w);
        o1.x = fmaf(v1.x, c1.x, h1.x); o1.y = fmaf(v1.y, c1.y, h1.y);
        o1.z = fmaf(v1.z, c1.z, h1.z); o1.w = fmaf(v1.w, c1.w, h1.w);
        o2.x = fmaf(v2.x, c2.x, h2.x); o2.y = fmaf(v2.y, c2.y, h2.y);
        o2.z = fmaf(v2.z, c2.z, h2.z); o2.w = fmaf(v2.w, c2.w, h2.w);
        o3.x = fmaf(v3.x, c3.x, h3.x); o3.y = fmaf(v3.y, c3.y, h3.y);
        o3.z = fmaf(v3.z, c3.z, h3.z); o3.w = fmaf(v3.w, c3.w, h3.w);

        y4[(size_t)r0 * 32 + f4] = o0;
        if (k1) y4[(size_t)r1 * 32 + f4] = o1;
        if (k2) y4[(size_t)r2 * 32 + f4] = o2;
        if (k3) y4[(size_t)r3 * 32 + f4] = o3;
    }
}

extern "C" void kernel_launch(void* const* d_in, const int* in_sizes, int n_in,
                              void* d_out, int out_size, void* d_ws, size_t ws_size,
                              hipStream_t stream)
{
    const float* x      = (const float*)d_in[0];
    const int*   labels = (const int*)d_in[1];
    const float* gamma  = (const float*)d_in[2];
    const float* beta   = (const float*)d_in[3];
    float* y  = (float*)d_out;
    float* ws = (float*)d_ws;
    const int N = in_sizes[1];

    // ws layout: [nb partials][NCHUNK chunk-partials][scale/shift 4096]
    const long floats = (long)(ws_size / sizeof(float));
    long avail = floats - (long)NCHUNK * PB - 4096;
    int nb = MAXNB;
    if ((long)nb * PB > avail) nb = (int)(avail / PB);
    if (nb < 1) nb = 1;
    const int chunk = (N + nb - 1) / nb;
    const int per   = (nb + NCHUNK - 1) / NCHUNK;

    float* ws2         = ws + (size_t)nb * PB;
    float* scale_shift = ws2 + (size_t)NCHUNK * PB;

    cbn_stats_kernel<<<nb, 256, 0, stream>>>(x, labels, ws, N, nb, chunk);
    cbn_reduce_kernel<<<dim3((PB + 255) / 256, NCHUNK), 256, 0, stream>>>(ws, ws2, nb, per);
    cbn_finalize_kernel<<<8, 256, 0, stream>>>(ws2, gamma, beta, scale_shift);
    cbn_apply_kernel<<<2048, 256, 0, stream>>>(x, labels, scale_shift, y, N);
}